// Round 5
// baseline (563.066 us; speedup 1.0000x reference)
//
#include <hip/hip_runtime.h>
#include <hip/hip_bf16.h>

// GCN: 3x GCNConv(relu) + mean-pool + linear + log_softmax
// N=100000 nodes, E=1600000 edges, F=128 -> 64 -> 64 -> 64, 256 graphs, 15 classes.
//
// Round 5 structure:
//  - norm folded into gather table: xwb[i] = bf16(dinv[i] * (h@W)[i])
//  - CSR build: hist (int4, 4 atomics in flight) -> 3-phase scan -> scatter
//    (int4 edge loads, fill memset-zeroed [SDMA path; shader-written fill was 2x slower],
//     pos = rowptr[d] + fill[d]++)
//  - layer 1: gemm_tile (fp32 in, bf16 pre-scaled out)
//  - layers 2,3: FUSED agg+gemm (aggregate 32 rows into LDS x-tile, then GEMM)
//  - layer 3 output: agg_final -> bf16 h3 -> pool -> head

#define N_GRAPHS 256
#define HIDDEN 64
#define N_CLASSES 15
#define TILE_ROWS 32
#define SCAN_CHUNK 1024  // per block: 256 threads x 4 elements

__device__ __forceinline__ float bf2f(ushort u) {
    return __uint_as_float(((unsigned int)u) << 16);
}
__device__ __forceinline__ ushort f2bf(float f) {
    __hip_bfloat16 h = __float2bfloat16(f);  // RNE
    return *reinterpret_cast<ushort*>(&h);
}

// ---------------- degree histogram (4 edges/thread via int4) ----------------
__global__ void hist_kernel(const int* __restrict__ dst, int* __restrict__ deg, int E) {
    int tid = blockIdx.x * blockDim.x + threadIdx.x;
    int e4 = E >> 2;
    if (tid < e4) {
        int4 d = reinterpret_cast<const int4*>(dst)[tid];
        atomicAdd(&deg[d.x], 1);
        atomicAdd(&deg[d.y], 1);
        atomicAdd(&deg[d.z], 1);
        atomicAdd(&deg[d.w], 1);
    }
    if (tid < (E & 3)) atomicAdd(&deg[dst[(E & ~3) + tid]], 1);
}

// ---------------- 3-phase device-wide exclusive scan of deg -> rowptr ----------------
__global__ __launch_bounds__(256) void scan_a_kernel(const int* __restrict__ deg,
                                                     int* __restrict__ bsum, int n) {
    int base = blockIdx.x * SCAN_CHUNK + threadIdx.x * 4;
    int s = 0;
#pragma unroll
    for (int j = 0; j < 4; ++j) {
        int i = base + j;
        if (i < n) s += deg[i];
    }
    __shared__ int ls[256];
    ls[threadIdx.x] = s;
    __syncthreads();
    for (int off = 128; off > 0; off >>= 1) {
        if (threadIdx.x < off) ls[threadIdx.x] += ls[threadIdx.x + off];
        __syncthreads();
    }
    if (threadIdx.x == 0) bsum[blockIdx.x] = ls[0];
}

__global__ __launch_bounds__(256) void scan_b_kernel(const int* __restrict__ bsum,
                                                     int* __restrict__ boff,
                                                     int* __restrict__ rowptr, int nb, int n) {
    __shared__ int s[256];
    int t = threadIdx.x;
    s[t] = (t < nb) ? bsum[t] : 0;
    __syncthreads();
    for (int off = 1; off < 256; off <<= 1) {
        int v = (t >= off) ? s[t - off] : 0;
        __syncthreads();
        s[t] += v;
        __syncthreads();
    }
    if (t < nb) boff[t] = (t == 0) ? 0 : s[t - 1];
    if (t == 0) rowptr[n] = s[255];
}

// per-block exclusive scan + offset -> rowptr; fused dinv = rsqrt(deg+1)
__global__ __launch_bounds__(256) void scan_c_kernel(const int* __restrict__ deg,
                                                     const int* __restrict__ boff,
                                                     int* __restrict__ rowptr,
                                                     float* __restrict__ dinv, int n) {
    int base = blockIdx.x * SCAN_CHUNK + threadIdx.x * 4;
    int v[4];
    int s = 0;
#pragma unroll
    for (int j = 0; j < 4; ++j) {
        int i = base + j;
        v[j] = (i < n) ? deg[i] : 0;
        s += v[j];
    }
    __shared__ int ls[256];
    ls[threadIdx.x] = s;
    __syncthreads();
    for (int off = 1; off < 256; off <<= 1) {
        int u = (threadIdx.x >= off) ? ls[threadIdx.x - off] : 0;
        __syncthreads();
        ls[threadIdx.x] += u;
        __syncthreads();
    }
    int run = boff[blockIdx.x] + ((threadIdx.x == 0) ? 0 : ls[threadIdx.x - 1]);
#pragma unroll
    for (int j = 0; j < 4; ++j) {
        int i = base + j;
        if (i < n) {
            rowptr[i] = run;
            dinv[i] = rsqrtf((float)(v[j] + 1));  // +1 = self-loop
            run += v[j];
        }
    }
}

// ---------------- CSR scatter: 4 edges/thread, fill zero-based (memset) ----------------
__global__ void scatter_kernel(const int* __restrict__ src, const int* __restrict__ dst,
                               const int* __restrict__ rowptr, int* __restrict__ fill,
                               int* __restrict__ col, int E) {
    int tid = blockIdx.x * blockDim.x + threadIdx.x;
    int e4 = E >> 2;
    if (tid < e4) {
        int4 d = reinterpret_cast<const int4*>(dst)[tid];
        int4 s = reinterpret_cast<const int4*>(src)[tid];
        int r0 = rowptr[d.x], r1 = rowptr[d.y], r2 = rowptr[d.z], r3 = rowptr[d.w];
        int p0 = atomicAdd(&fill[d.x], 1);
        int p1 = atomicAdd(&fill[d.y], 1);
        int p2 = atomicAdd(&fill[d.z], 1);
        int p3 = atomicAdd(&fill[d.w], 1);
        col[r0 + p0] = s.x;
        col[r1 + p1] = s.y;
        col[r2 + p2] = s.z;
        col[r3 + p3] = s.w;
    }
    if (tid < (E & 3)) {
        int e = (E & ~3) + tid;
        int d = dst[e];
        int pos = rowptr[d] + atomicAdd(&fill[d], 1);
        col[pos] = src[e];
    }
}

// ---------------- GEMM (layer 1): XWB(bf16) = dinv .* (X @ W) ----------------
// block = 256 threads (4 waves), one 32-row tile per block, grid-stride.
template <int FIN>
__global__ __launch_bounds__(256) void gemm_tile_kernel(const float* __restrict__ X,
                                                        const float* __restrict__ W,
                                                        const float* __restrict__ dinv,
                                                        ushort* __restrict__ XWB, int n) {
    __shared__ float xt[TILE_ROWS][FIN];
    __shared__ float wl[FIN * 64];
    for (int i = threadIdx.x; i < FIN * 64; i += 256) wl[i] = W[i];

    int lane = threadIdx.x & 63;
    int w = threadIdx.x >> 6;
    int ntiles = (n + TILE_ROWS - 1) / TILE_ROWS;

    for (int t = blockIdx.x; t < ntiles; t += gridDim.x) {
        int row0 = t * TILE_ROWS;
        __syncthreads();  // xt reuse guard (also covers initial wl stage)
        const int NF4 = TILE_ROWS * FIN / 4;
        for (int i = threadIdx.x; i < NF4; i += 256) {
            int r = i / (FIN / 4), k4 = i % (FIN / 4);
            int row = row0 + r;
            float4 v;
            if (row < n) v = *reinterpret_cast<const float4*>(X + (size_t)row * FIN + k4 * 4);
            else v = make_float4(0.f, 0.f, 0.f, 0.f);
            *reinterpret_cast<float4*>(&xt[r][k4 * 4]) = v;
        }
        __syncthreads();

        int r0 = w * 8;
        float acc[8] = {0.f, 0.f, 0.f, 0.f, 0.f, 0.f, 0.f, 0.f};
#pragma unroll 8
        for (int k = 0; k < FIN; ++k) {
            float wv = wl[k * 64 + lane];
#pragma unroll
            for (int j = 0; j < 8; ++j) acc[j] += xt[r0 + j][k] * wv;
        }
#pragma unroll
        for (int j = 0; j < 8; ++j) {
            int row = row0 + r0 + j;
            if (row < n) XWB[(size_t)row * 64 + lane] = f2bf(dinv[row] * acc[j]);
        }
    }
}

// ---------------- FUSED agg(layer k) + gemm(layer k+1) ----------------
// Block = 32 rows. Wave w aggregates rows w*8..w*8+7 from XWB_prev into LDS x-tile
// (h = relu(dinv*(self + sum) + b), fp32), then the block GEMMs the tile with W,
// writing XWB_next = dinv .* (h @ W) in bf16.
__global__ __launch_bounds__(256) void agg_gemm_kernel(const ushort* __restrict__ XWB_prev,
                                                       const int* __restrict__ rowptr,
                                                       const int* __restrict__ col,
                                                       const float* __restrict__ dinv,
                                                       const float* __restrict__ bias,
                                                       const float* __restrict__ W,
                                                       ushort* __restrict__ XWB_next, int n) {
    __shared__ float xt[TILE_ROWS][64];
    __shared__ float wl[64 * 64];
    for (int i = threadIdx.x; i < 64 * 64; i += 256) wl[i] = W[i];

    int lane = threadIdx.x & 63;
    int w = threadIdx.x >> 6;
    int row0 = blockIdx.x * TILE_ROWS;
    float b = bias[lane];

    int r0 = w * 8;
#pragma unroll
    for (int j = 0; j < 8; ++j) {
        int i = row0 + r0 + j;
        float h = 0.f;
        if (i < n) {
            float a0 = bf2f(XWB_prev[(size_t)i * 64 + lane]);  // self-loop (pre-scaled)
            float a1 = 0.f, a2 = 0.f, a3 = 0.f, a4 = 0.f, a5 = 0.f, a6 = 0.f, a7 = 0.f;
            int p0 = __builtin_amdgcn_readfirstlane(rowptr[i]);
            int p1 = __builtin_amdgcn_readfirstlane(rowptr[i + 1]);
            int p = p0;
            for (; p + 8 <= p1; p += 8) {
                int c0 = col[p], c1 = col[p + 1], c2 = col[p + 2], c3 = col[p + 3];
                int c4 = col[p + 4], c5 = col[p + 5], c6 = col[p + 6], c7 = col[p + 7];
                a0 += bf2f(XWB_prev[(size_t)c0 * 64 + lane]);
                a1 += bf2f(XWB_prev[(size_t)c1 * 64 + lane]);
                a2 += bf2f(XWB_prev[(size_t)c2 * 64 + lane]);
                a3 += bf2f(XWB_prev[(size_t)c3 * 64 + lane]);
                a4 += bf2f(XWB_prev[(size_t)c4 * 64 + lane]);
                a5 += bf2f(XWB_prev[(size_t)c5 * 64 + lane]);
                a6 += bf2f(XWB_prev[(size_t)c6 * 64 + lane]);
                a7 += bf2f(XWB_prev[(size_t)c7 * 64 + lane]);
            }
            for (; p < p1; ++p) {
                a0 += bf2f(XWB_prev[(size_t)col[p] * 64 + lane]);
            }
            float sum = ((a0 + a1) + (a2 + a3)) + ((a4 + a5) + (a6 + a7));
            h = fmaxf(dinv[i] * sum + b, 0.f);
        }
        xt[r0 + j][lane] = h;
    }
    __syncthreads();

    float acc[8] = {0.f, 0.f, 0.f, 0.f, 0.f, 0.f, 0.f, 0.f};
#pragma unroll 8
    for (int k = 0; k < 64; ++k) {
        float wv = wl[k * 64 + lane];
#pragma unroll
        for (int j = 0; j < 8; ++j) acc[j] += xt[r0 + j][k] * wv;
    }
#pragma unroll
    for (int j = 0; j < 8; ++j) {
        int row = row0 + r0 + j;
        if (row < n) XWB_next[(size_t)row * 64 + lane] = f2bf(dinv[row] * acc[j]);
    }
}

// ---------------- final aggregate (layer 3): h3 = relu(dinv*(self+sum) + b), bf16 ----------------
__global__ __launch_bounds__(256) void agg_final_kernel(const ushort* __restrict__ XWB,
                                                        const int* __restrict__ rowptr,
                                                        const int* __restrict__ col,
                                                        const float* __restrict__ dinv,
                                                        const float* __restrict__ bias,
                                                        ushort* __restrict__ OUT, int n) {
    int lane = threadIdx.x & 63;
    int wid = (blockIdx.x * blockDim.x + threadIdx.x) >> 6;
    int nw = (gridDim.x * blockDim.x) >> 6;
    float b = bias[lane];
    for (int i = wid; i < n; i += nw) {
        float a0 = bf2f(XWB[(size_t)i * 64 + lane]);
        float a1 = 0.f, a2 = 0.f, a3 = 0.f, a4 = 0.f, a5 = 0.f, a6 = 0.f, a7 = 0.f;
        int p0 = __builtin_amdgcn_readfirstlane(rowptr[i]);
        int p1 = __builtin_amdgcn_readfirstlane(rowptr[i + 1]);
        int p = p0;
        for (; p + 8 <= p1; p += 8) {
            int c0 = col[p], c1 = col[p + 1], c2 = col[p + 2], c3 = col[p + 3];
            int c4 = col[p + 4], c5 = col[p + 5], c6 = col[p + 6], c7 = col[p + 7];
            a0 += bf2f(XWB[(size_t)c0 * 64 + lane]);
            a1 += bf2f(XWB[(size_t)c1 * 64 + lane]);
            a2 += bf2f(XWB[(size_t)c2 * 64 + lane]);
            a3 += bf2f(XWB[(size_t)c3 * 64 + lane]);
            a4 += bf2f(XWB[(size_t)c4 * 64 + lane]);
            a5 += bf2f(XWB[(size_t)c5 * 64 + lane]);
            a6 += bf2f(XWB[(size_t)c6 * 64 + lane]);
            a7 += bf2f(XWB[(size_t)c7 * 64 + lane]);
        }
        for (; p < p1; ++p) {
            a0 += bf2f(XWB[(size_t)col[p] * 64 + lane]);
        }
        float sum = ((a0 + a1) + (a2 + a3)) + ((a4 + a5) + (a6 + a7));
        float acc = dinv[i] * sum + b;
        OUT[(size_t)i * 64 + lane] = f2bf(fmaxf(acc, 0.f));
    }
}

// ---------------- mean pool (batch is sorted; H is bf16) ----------------
__global__ void pool_kernel(const ushort* __restrict__ H, const int* __restrict__ batch,
                            float* __restrict__ pooled, int n) {
    int g = blockIdx.x;
    int lo = 0, hi = n;
    while (lo < hi) { int mid = (lo + hi) >> 1; if (batch[mid] < g) lo = mid + 1; else hi = mid; }
    int start = lo;
    lo = 0; hi = n;
    while (lo < hi) { int mid = (lo + hi) >> 1; if (batch[mid] < g + 1) lo = mid + 1; else hi = mid; }
    int end = lo;

    int lane = threadIdx.x & 63;
    int w = threadIdx.x >> 6;
    __shared__ float part[4][64];
    float acc = 0.f;
    for (int i = start + w; i < end; i += 4) acc += bf2f(H[(size_t)i * 64 + lane]);
    part[w][lane] = acc;
    __syncthreads();
    if (w == 0) {
        float s = part[0][lane] + part[1][lane] + part[2][lane] + part[3][lane];
        float cnt = (float)(end - start);
        pooled[g * 64 + lane] = s / fmaxf(cnt, 1.0f);
    }
}

// ---------------- head ----------------
__global__ void head_kernel(const float* __restrict__ pooled, const float* __restrict__ fcw,
                            const float* __restrict__ fcb, float* __restrict__ out) {
    __shared__ float w[64 * N_CLASSES];
    __shared__ float bb[N_CLASSES];
    for (int i = threadIdx.x; i < 64 * N_CLASSES; i += blockDim.x) w[i] = fcw[i];
    if (threadIdx.x < N_CLASSES) bb[threadIdx.x] = fcb[threadIdx.x];
    __syncthreads();
    int g = threadIdx.x;  // 256 threads, one per graph
    float logits[N_CLASSES];
    float m = -1e30f;
    const float* pr = pooled + g * 64;
    for (int c = 0; c < N_CLASSES; ++c) {
        float acc = bb[c];
        for (int k = 0; k < 64; ++k) acc += pr[k] * w[k * N_CLASSES + c];
        logits[c] = acc;
        m = fmaxf(m, acc);
    }
    float se = 0.f;
    for (int c = 0; c < N_CLASSES; ++c) se += expf(logits[c] - m);
    float lse = m + logf(se);
    for (int c = 0; c < N_CLASSES; ++c) out[g * N_CLASSES + c] = logits[c] - lse;
}

extern "C" void kernel_launch(void* const* d_in, const int* in_sizes, int n_in,
                              void* d_out, int out_size, void* d_ws, size_t ws_size,
                              hipStream_t stream) {
    const float* x    = (const float*)d_in[0];
    const float* w1   = (const float*)d_in[1];
    const float* b1   = (const float*)d_in[2];
    const float* w2   = (const float*)d_in[3];
    const float* b2   = (const float*)d_in[4];
    const float* w3   = (const float*)d_in[5];
    const float* b3   = (const float*)d_in[6];
    const float* fcw  = (const float*)d_in[7];
    const float* fcb  = (const float*)d_in[8];
    const int*   ei   = (const int*)d_in[9];
    const int*   batch = (const int*)d_in[10];

    const int N = in_sizes[10];       // 100000
    const int E = in_sizes[9] / 2;    // 1600000
    const int* src = ei;
    const int* dst = ei + E;

    char* ws = (char*)d_ws;
    size_t off = 0;
    auto alloc = [&](size_t bytes) -> void* {
        void* p = ws + off;
        off += (bytes + 255) & ~(size_t)255;
        return p;
    };
    int*    deg    = (int*)alloc((size_t)N * 4);
    int*    rowptr = (int*)alloc(((size_t)N + 1) * 4);
    int*    fill   = (int*)alloc((size_t)N * 4);
    int*    col    = (int*)alloc((size_t)E * 4);
    float*  dinv   = (float*)alloc((size_t)N * 4);
    ushort* xwbA   = (ushort*)alloc((size_t)N * 64 * 2);  // bf16 pre-scaled tables (ping-pong)
    ushort* xwbB   = (ushort*)alloc((size_t)N * 64 * 2);
    ushort* h3     = (ushort*)alloc((size_t)N * 64 * 2);  // bf16 final h
    float*  pooled = (float*)alloc((size_t)N_GRAPHS * 64 * 4);
    int*    bsum   = (int*)alloc(256 * 4);
    int*    boff   = (int*)alloc(256 * 4);
    (void)ws_size;

    // SDMA-path zeroing (shader-written fill measured 2x slower atomics — L2-dirty lines)
    hipMemsetAsync(deg, 0, (size_t)N * 4, stream);
    hipMemsetAsync(fill, 0, (size_t)N * 4, stream);

    const int nb = (N + SCAN_CHUNK - 1) / SCAN_CHUNK;   // 98
    const int eb = ((E >> 2) + 255) / 256;              // 1563
    const int GB = 2048;

    hist_kernel<<<eb, 256, 0, stream>>>(dst, deg, E);
    scan_a_kernel<<<nb, 256, 0, stream>>>(deg, bsum, N);
    scan_b_kernel<<<1, 256, 0, stream>>>(bsum, boff, rowptr, nb, N);
    scan_c_kernel<<<nb, 256, 0, stream>>>(deg, boff, rowptr, dinv, N);
    scatter_kernel<<<eb, 256, 0, stream>>>(src, dst, rowptr, fill, col, E);

    int ntiles = (N + TILE_ROWS - 1) / TILE_ROWS;  // 3125

    // layer 1: gemm only (table A)
    gemm_tile_kernel<128><<<ntiles, 256, 0, stream>>>(x, w1, dinv, xwbA, N);
    // layer 2 = agg(layer1) + gemm(w2): A -> B
    agg_gemm_kernel<<<ntiles, 256, 0, stream>>>(xwbA, rowptr, col, dinv, b1, w2, xwbB, N);
    // layer 3 = agg(layer2) + gemm(w3): B -> A
    agg_gemm_kernel<<<ntiles, 256, 0, stream>>>(xwbB, rowptr, col, dinv, b2, w3, xwbA, N);
    // final aggregate -> h3
    agg_final_kernel<<<GB, 256, 0, stream>>>(xwbA, rowptr, col, dinv, b3, h3, N);

    pool_kernel<<<N_GRAPHS, 256, 0, stream>>>(h3, batch, pooled, N);
    head_kernel<<<1, 256, 0, stream>>>(pooled, fcw, fcb, (float*)d_out);
}

// Round 6
// 457.831 us; speedup vs baseline: 1.2299x; 1.2299x over previous
//
#include <hip/hip_runtime.h>
#include <hip/hip_bf16.h>

// GCN: 3x GCNConv(relu) + mean-pool + linear + log_softmax
// N=100000 nodes, E=1600000 edges, F=128 -> 64 -> 64 -> 64, 256 graphs, 15 classes.
//
// Round 6 structure (reconstruction + 1 experiment):
//  - norm folded into gather table: xwb[i] = bf16(dinv[i] * (h@W)[i])
//  - hist/scatter: round-3 grid-stride 1-edge/thread shape (measured 77us),
//    scatter delta vs r3: col-only 4B store (THE experiment; r4/r5's 133us suspects)
//  - separate gemm + agg kernels (r4 pipeline; fusion measured +70us in r5 -> reverted)
//  - layers 2/3 gemm reads bf16 h; all aggs read bf16 pre-scaled tables

#define N_GRAPHS 256
#define HIDDEN 64
#define N_CLASSES 15
#define TILE_ROWS 32
#define SCAN_CHUNK 1024  // per block: 256 threads x 4 elements

__device__ __forceinline__ float bf2f(ushort u) {
    return __uint_as_float(((unsigned int)u) << 16);
}
__device__ __forceinline__ ushort f2bf(float f) {
    __hip_bfloat16 h = __float2bfloat16(f);  // RNE
    return *reinterpret_cast<ushort*>(&h);
}

// ---------------- degree histogram (r3 shape: grid-stride, 1 edge/thread) ----------------
__global__ void hist_kernel(const int* __restrict__ dst, int* __restrict__ deg, int E) {
    for (int e = blockIdx.x * blockDim.x + threadIdx.x; e < E; e += gridDim.x * blockDim.x) {
        atomicAdd(&deg[dst[e]], 1);
    }
}

// ---------------- 3-phase device-wide exclusive scan of deg -> rowptr ----------------
__global__ __launch_bounds__(256) void scan_a_kernel(const int* __restrict__ deg,
                                                     int* __restrict__ bsum, int n) {
    int base = blockIdx.x * SCAN_CHUNK + threadIdx.x * 4;
    int s = 0;
#pragma unroll
    for (int j = 0; j < 4; ++j) {
        int i = base + j;
        if (i < n) s += deg[i];
    }
    __shared__ int ls[256];
    ls[threadIdx.x] = s;
    __syncthreads();
    for (int off = 128; off > 0; off >>= 1) {
        if (threadIdx.x < off) ls[threadIdx.x] += ls[threadIdx.x + off];
        __syncthreads();
    }
    if (threadIdx.x == 0) bsum[blockIdx.x] = ls[0];
}

__global__ __launch_bounds__(256) void scan_b_kernel(const int* __restrict__ bsum,
                                                     int* __restrict__ boff,
                                                     int* __restrict__ rowptr, int nb, int n) {
    __shared__ int s[256];
    int t = threadIdx.x;
    s[t] = (t < nb) ? bsum[t] : 0;
    __syncthreads();
    for (int off = 1; off < 256; off <<= 1) {
        int v = (t >= off) ? s[t - off] : 0;
        __syncthreads();
        s[t] += v;
        __syncthreads();
    }
    if (t < nb) boff[t] = (t == 0) ? 0 : s[t - 1];
    if (t == 0) rowptr[n] = s[255];
}

// per-block exclusive scan + offset -> rowptr; fused dinv = rsqrt(deg+1)
__global__ __launch_bounds__(256) void scan_c_kernel(const int* __restrict__ deg,
                                                     const int* __restrict__ boff,
                                                     int* __restrict__ rowptr,
                                                     float* __restrict__ dinv, int n) {
    int base = blockIdx.x * SCAN_CHUNK + threadIdx.x * 4;
    int v[4];
    int s = 0;
#pragma unroll
    for (int j = 0; j < 4; ++j) {
        int i = base + j;
        v[j] = (i < n) ? deg[i] : 0;
        s += v[j];
    }
    __shared__ int ls[256];
    ls[threadIdx.x] = s;
    __syncthreads();
    for (int off = 1; off < 256; off <<= 1) {
        int u = (threadIdx.x >= off) ? ls[threadIdx.x - off] : 0;
        __syncthreads();
        ls[threadIdx.x] += u;
        __syncthreads();
    }
    int run = boff[blockIdx.x] + ((threadIdx.x == 0) ? 0 : ls[threadIdx.x - 1]);
#pragma unroll
    for (int j = 0; j < 4; ++j) {
        int i = base + j;
        if (i < n) {
            rowptr[i] = run;
            dinv[i] = rsqrtf((float)(v[j] + 1));  // +1 = self-loop
            run += v[j];
        }
    }
}

// ---------------- CSR scatter (r3 loop shape; delta = 4B col-only store) ----------------
__global__ void scatter_kernel(const int* __restrict__ src, const int* __restrict__ dst,
                               const int* __restrict__ rowptr, int* __restrict__ fill,
                               int* __restrict__ col, int E) {
    for (int e = blockIdx.x * blockDim.x + threadIdx.x; e < E; e += gridDim.x * blockDim.x) {
        int d = dst[e], s = src[e];
        int pos = rowptr[d] + atomicAdd(&fill[d], 1);
        col[pos] = s;
    }
}

// ---------------- GEMM: XWB(bf16) = dinv .* (X @ W), tiled ----------------
// block = 256 threads (4 waves). One 32-row tile per block, grid-stride.
// LDS: X-tile [32][FIN] (fp32) + W [FIN][64]. Wave w computes rows w*8..w*8+7, lane = col.
template <int FIN, typename TIN>
__global__ __launch_bounds__(256) void gemm_tile_kernel(const TIN* __restrict__ X,
                                                        const float* __restrict__ W,
                                                        const float* __restrict__ dinv,
                                                        ushort* __restrict__ XWB, int n) {
    __shared__ float xt[TILE_ROWS][FIN];
    __shared__ float wl[FIN * 64];
    for (int i = threadIdx.x; i < FIN * 64; i += 256) wl[i] = W[i];

    int lane = threadIdx.x & 63;
    int w = threadIdx.x >> 6;
    int ntiles = (n + TILE_ROWS - 1) / TILE_ROWS;

    for (int t = blockIdx.x; t < ntiles; t += gridDim.x) {
        int row0 = t * TILE_ROWS;
        __syncthreads();  // xt reuse guard (also covers initial wl stage)
        if constexpr (sizeof(TIN) == 4) {
            const int NF4 = TILE_ROWS * FIN / 4;  // float4 chunks
            for (int i = threadIdx.x; i < NF4; i += 256) {
                int r = i / (FIN / 4), k4 = i % (FIN / 4);
                int row = row0 + r;
                float4 v;
                if (row < n) v = *reinterpret_cast<const float4*>((const float*)X + (size_t)row * FIN + k4 * 4);
                else v = make_float4(0.f, 0.f, 0.f, 0.f);
                *reinterpret_cast<float4*>(&xt[r][k4 * 4]) = v;
            }
        } else {
            const int NC8 = TILE_ROWS * FIN / 8;  // 8 bf16 = 16B chunks
            for (int i = threadIdx.x; i < NC8; i += 256) {
                int r = i / (FIN / 8), k8 = i % (FIN / 8);
                int row = row0 + r;
                uint4 v = make_uint4(0u, 0u, 0u, 0u);
                if (row < n) v = *reinterpret_cast<const uint4*>((const ushort*)X + (size_t)row * FIN + k8 * 8);
                float* dstp = &xt[r][k8 * 8];
                dstp[0] = bf2f((ushort)(v.x & 0xffff));
                dstp[1] = bf2f((ushort)(v.x >> 16));
                dstp[2] = bf2f((ushort)(v.y & 0xffff));
                dstp[3] = bf2f((ushort)(v.y >> 16));
                dstp[4] = bf2f((ushort)(v.z & 0xffff));
                dstp[5] = bf2f((ushort)(v.z >> 16));
                dstp[6] = bf2f((ushort)(v.w & 0xffff));
                dstp[7] = bf2f((ushort)(v.w >> 16));
            }
        }
        __syncthreads();

        int r0 = w * 8;
        float acc[8] = {0.f, 0.f, 0.f, 0.f, 0.f, 0.f, 0.f, 0.f};
#pragma unroll 8
        for (int k = 0; k < FIN; ++k) {
            float wv = wl[k * 64 + lane];
#pragma unroll
            for (int j = 0; j < 8; ++j) acc[j] += xt[r0 + j][k] * wv;
        }
#pragma unroll
        for (int j = 0; j < 8; ++j) {
            int row = row0 + r0 + j;
            if (row < n) XWB[(size_t)row * 64 + lane] = f2bf(dinv[row] * acc[j]);
        }
    }
}

// ---------------- CSR aggregation: h = relu(dinv[i]*(xwb[i] + sum xwb[col]) + b), bf16 out ----------------
__global__ __launch_bounds__(256) void agg_csr_kernel(const ushort* __restrict__ XWB,
                                                      const int* __restrict__ rowptr,
                                                      const int* __restrict__ col,
                                                      const float* __restrict__ dinv,
                                                      const float* __restrict__ bias,
                                                      ushort* __restrict__ OUT, int n) {
    int lane = threadIdx.x & 63;
    int wid = (blockIdx.x * blockDim.x + threadIdx.x) >> 6;
    int nw = (gridDim.x * blockDim.x) >> 6;
    float b = bias[lane];
    for (int i = wid; i < n; i += nw) {
        float a0 = bf2f(XWB[(size_t)i * 64 + lane]);  // self-loop (pre-scaled)
        float a1 = 0.f, a2 = 0.f, a3 = 0.f, a4 = 0.f, a5 = 0.f, a6 = 0.f, a7 = 0.f;
        int p0 = __builtin_amdgcn_readfirstlane(rowptr[i]);
        int p1 = __builtin_amdgcn_readfirstlane(rowptr[i + 1]);
        int p = p0;
        for (; p + 8 <= p1; p += 8) {
            int c0 = col[p], c1 = col[p + 1], c2 = col[p + 2], c3 = col[p + 3];
            int c4 = col[p + 4], c5 = col[p + 5], c6 = col[p + 6], c7 = col[p + 7];
            a0 += bf2f(XWB[(size_t)c0 * 64 + lane]);
            a1 += bf2f(XWB[(size_t)c1 * 64 + lane]);
            a2 += bf2f(XWB[(size_t)c2 * 64 + lane]);
            a3 += bf2f(XWB[(size_t)c3 * 64 + lane]);
            a4 += bf2f(XWB[(size_t)c4 * 64 + lane]);
            a5 += bf2f(XWB[(size_t)c5 * 64 + lane]);
            a6 += bf2f(XWB[(size_t)c6 * 64 + lane]);
            a7 += bf2f(XWB[(size_t)c7 * 64 + lane]);
        }
        for (; p < p1; ++p) {
            a0 += bf2f(XWB[(size_t)col[p] * 64 + lane]);
        }
        float sum = ((a0 + a1) + (a2 + a3)) + ((a4 + a5) + (a6 + a7));
        float acc = dinv[i] * sum + b;
        OUT[(size_t)i * 64 + lane] = f2bf(fmaxf(acc, 0.f));
    }
}

// ---------------- mean pool (batch is sorted; H is bf16) ----------------
__global__ void pool_kernel(const ushort* __restrict__ H, const int* __restrict__ batch,
                            float* __restrict__ pooled, int n) {
    int g = blockIdx.x;
    int lo = 0, hi = n;
    while (lo < hi) { int mid = (lo + hi) >> 1; if (batch[mid] < g) lo = mid + 1; else hi = mid; }
    int start = lo;
    lo = 0; hi = n;
    while (lo < hi) { int mid = (lo + hi) >> 1; if (batch[mid] < g + 1) lo = mid + 1; else hi = mid; }
    int end = lo;

    int lane = threadIdx.x & 63;
    int w = threadIdx.x >> 6;
    __shared__ float part[4][64];
    float acc = 0.f;
    for (int i = start + w; i < end; i += 4) acc += bf2f(H[(size_t)i * 64 + lane]);
    part[w][lane] = acc;
    __syncthreads();
    if (w == 0) {
        float s = part[0][lane] + part[1][lane] + part[2][lane] + part[3][lane];
        float cnt = (float)(end - start);
        pooled[g * 64 + lane] = s / fmaxf(cnt, 1.0f);
    }
}

// ---------------- head ----------------
__global__ void head_kernel(const float* __restrict__ pooled, const float* __restrict__ fcw,
                            const float* __restrict__ fcb, float* __restrict__ out) {
    __shared__ float w[64 * N_CLASSES];
    __shared__ float bb[N_CLASSES];
    for (int i = threadIdx.x; i < 64 * N_CLASSES; i += blockDim.x) w[i] = fcw[i];
    if (threadIdx.x < N_CLASSES) bb[threadIdx.x] = fcb[threadIdx.x];
    __syncthreads();
    int g = threadIdx.x;  // 256 threads, one per graph
    float logits[N_CLASSES];
    float m = -1e30f;
    const float* pr = pooled + g * 64;
    for (int c = 0; c < N_CLASSES; ++c) {
        float acc = bb[c];
        for (int k = 0; k < 64; ++k) acc += pr[k] * w[k * N_CLASSES + c];
        logits[c] = acc;
        m = fmaxf(m, acc);
    }
    float se = 0.f;
    for (int c = 0; c < N_CLASSES; ++c) se += expf(logits[c] - m);
    float lse = m + logf(se);
    for (int c = 0; c < N_CLASSES; ++c) out[g * N_CLASSES + c] = logits[c] - lse;
}

extern "C" void kernel_launch(void* const* d_in, const int* in_sizes, int n_in,
                              void* d_out, int out_size, void* d_ws, size_t ws_size,
                              hipStream_t stream) {
    const float* x    = (const float*)d_in[0];
    const float* w1   = (const float*)d_in[1];
    const float* b1   = (const float*)d_in[2];
    const float* w2   = (const float*)d_in[3];
    const float* b2   = (const float*)d_in[4];
    const float* w3   = (const float*)d_in[5];
    const float* b3   = (const float*)d_in[6];
    const float* fcw  = (const float*)d_in[7];
    const float* fcb  = (const float*)d_in[8];
    const int*   ei   = (const int*)d_in[9];
    const int*   batch = (const int*)d_in[10];

    const int N = in_sizes[10];       // 100000
    const int E = in_sizes[9] / 2;    // 1600000
    const int* src = ei;
    const int* dst = ei + E;

    char* ws = (char*)d_ws;
    size_t off = 0;
    auto alloc = [&](size_t bytes) -> void* {
        void* p = ws + off;
        off += (bytes + 255) & ~(size_t)255;
        return p;
    };
    int*    deg    = (int*)alloc((size_t)N * 4);
    int*    rowptr = (int*)alloc(((size_t)N + 1) * 4);
    int*    fill   = (int*)alloc((size_t)N * 4);
    int*    col    = (int*)alloc((size_t)E * 4);
    float*  dinv   = (float*)alloc((size_t)N * 4);
    ushort* xwb    = (ushort*)alloc((size_t)N * 64 * 2);  // bf16 pre-scaled gather table
    ushort* hbuf   = (ushort*)alloc((size_t)N * 64 * 2);  // bf16 h
    float*  pooled = (float*)alloc((size_t)N_GRAPHS * 64 * 4);
    int*    bsum   = (int*)alloc(256 * 4);
    int*    boff   = (int*)alloc(256 * 4);
    (void)ws_size;

    hipMemsetAsync(deg, 0, (size_t)N * 4, stream);
    hipMemsetAsync(fill, 0, (size_t)N * 4, stream);

    const int GB = 2048;
    const int nb = (N + SCAN_CHUNK - 1) / SCAN_CHUNK;  // 98 blocks

    hist_kernel<<<GB, 256, 0, stream>>>(dst, deg, E);
    scan_a_kernel<<<nb, 256, 0, stream>>>(deg, bsum, N);
    scan_b_kernel<<<1, 256, 0, stream>>>(bsum, boff, rowptr, nb, N);
    scan_c_kernel<<<nb, 256, 0, stream>>>(deg, boff, rowptr, dinv, N);
    scatter_kernel<<<GB, 256, 0, stream>>>(src, dst, rowptr, fill, col, E);

    int ntiles = (N + TILE_ROWS - 1) / TILE_ROWS;  // 3125

    // layer 1
    gemm_tile_kernel<128, float><<<ntiles, 256, 0, stream>>>(x, w1, dinv, xwb, N);
    agg_csr_kernel<<<GB, 256, 0, stream>>>(xwb, rowptr, col, dinv, b1, hbuf, N);
    // layer 2
    gemm_tile_kernel<64, ushort><<<ntiles, 256, 0, stream>>>(hbuf, w2, dinv, xwb, N);
    agg_csr_kernel<<<GB, 256, 0, stream>>>(xwb, rowptr, col, dinv, b2, hbuf, N);
    // layer 3
    gemm_tile_kernel<64, ushort><<<ntiles, 256, 0, stream>>>(hbuf, w3, dinv, xwb, N);
    agg_csr_kernel<<<GB, 256, 0, stream>>>(xwb, rowptr, col, dinv, b3, hbuf, N);

    pool_kernel<<<N_GRAPHS, 256, 0, stream>>>(hbuf, batch, pooled, N);
    head_kernel<<<1, 256, 0, stream>>>(pooled, fcw, fcb, (float*)d_out);
}